// Round 1
// 405.991 us; speedup vs baseline: 1.0444x; 1.0444x over previous
//
#include <hip/hip_runtime.h>
#include <hip/hip_bf16.h>

typedef _Float16 fp16_t;
typedef __attribute__((ext_vector_type(8))) _Float16 fp16x8;
typedef __attribute__((ext_vector_type(4))) _Float16 fp16x4;
typedef __attribute__((ext_vector_type(4))) float fx4;

#define GLDS(g, l)                                                              \
  __builtin_amdgcn_global_load_lds(                                             \
      (const __attribute__((address_space(1))) void*)(g),                       \
      (__attribute__((address_space(3))) void*)(l), 16, 0, 0)

enum { EPI_F32 = 0, EPI_F16 = 1, EPI_FUSE = 2 };

// ---------------------------------------------------------------------------
// XCD-aware block remap. HW assigns blocks to XCDs round-robin by linear id;
// we invert that so blocks sharing an A-strip (same by,bz; all bx) run
// consecutively on ONE XCD -> A-strip re-reads hit that XCD's L2.
// Requires gridDim.y*gridDim.z divisible by 8 (all our grids satisfy this).
// ---------------------------------------------------------------------------
__device__ __forceinline__ void xcd_decode(int& bx, int& by, int& bz) {
  const int nx = gridDim.x, ny = gridDim.y;
  const int lid = (int)(blockIdx.x + nx * (blockIdx.y + ny * blockIdx.z));
  const int j = lid & 7, k = lid >> 3;
  bx = k % nx;
  const int s = j + 8 * (k / nx);
  by = s % ny;
  bz = s / ny;
}

// ---------------------------------------------------------------------------
// BT-layout fp16 GEMM: C = A1·B1^T (+ A2·B1^T if ASPLIT)
// A: [M,K] row-major with leading dim lda, B: [N,K] row-major leading dim ldb.
// Tile 128x128, BK=32, 4 waves. global_load_lds staging with bank-conflict
// swizzle (verified: 0 conflicts).
// ---------------------------------------------------------------------------
template <bool ASPLIT, int EPI>
__global__ __launch_bounds__(256) void gemm_bt(
    const fp16_t* __restrict__ A1, const fp16_t* __restrict__ A2,
    const fp16_t* __restrict__ B1, void* __restrict__ Cv, int K, int lda,
    int ldb, long long sA, long long sB, long long sC,
    const float* __restrict__ bias, const float* __restrict__ resid) {
  constexpr int ALO = ASPLIT ? 128 * 32 : 0;
  __shared__ __align__(16) fp16_t As[128 * 32 + ALO];
  __shared__ __align__(16) fp16_t Bs[128 * 32];

  const int tid  = threadIdx.x;
  const int lane = tid & 63;
  const int w    = tid >> 6;
  const int wr   = w >> 1;
  const int wc   = w & 1;

  int bx, by, bz;
  xcd_decode(bx, by, bz);
  const int N = (int)gridDim.x * 128;
  const long long tile_m = (long long)by * 128;
  const long long tile_n = (long long)bx * 128;
  const long long z = bz;
  const long long aoff = z * sA + tile_m * (long long)lda;
  const long long boff = z * sB + tile_n * (long long)ldb;

  fx4 acc[4][4];
#pragma unroll
  for (int i = 0; i < 4; i++)
#pragma unroll
    for (int j = 0; j < 4; j++) acc[i][j] = (fx4){0.f, 0.f, 0.f, 0.f};

  // staging swizzle: LDS slot m holds global chunk (m+(r>>1))&3 of row r
  const int r_l = lane >> 2;
  const int c_l = ((((lane & 3) + ((r_l >> 1) & 3)) & 3) << 3);
  const int frow = lane & 15;
  const int qoff = (((lane >> 4) - ((frow >> 1) & 3)) & 3) << 3;

  const size_t sa0 = (size_t)(w * 16 + r_l) * lda + c_l;
  const size_t sa1 = (size_t)(64 + w * 16 + r_l) * lda + c_l;
  const size_t sb0 = (size_t)(w * 16 + r_l) * ldb + c_l;
  const size_t sb1 = (size_t)(64 + w * 16 + r_l) * ldb + c_l;
  const int ld0 = (w * 16) * 32;
  const int ld1 = (64 + w * 16) * 32;

  for (int kt = 0; kt < K; kt += 32) {
    __syncthreads();
    {
      const fp16_t* gah = A1 + aoff + kt;
      const fp16_t* gbh = B1 + boff + kt;
      GLDS(gah + sa0, &As[ld0]);
      GLDS(gah + sa1, &As[ld1]);
      GLDS(gbh + sb0, &Bs[ld0]);
      GLDS(gbh + sb1, &Bs[ld1]);
      if (ASPLIT) {
        const fp16_t* gal = A2 + aoff + kt;
        GLDS(gal + sa0, &As[ALO + ld0]);
        GLDS(gal + sa1, &As[ALO + ld1]);
      }
    }
    __syncthreads();

    fp16x8 afh[4], bbh[4], afl[4];
#pragma unroll
    for (int mi = 0; mi < 4; mi++)
      afh[mi] = *(const fp16x8*)&As[(wr * 64 + mi * 16 + frow) * 32 + qoff];
#pragma unroll
    for (int ni = 0; ni < 4; ni++)
      bbh[ni] = *(const fp16x8*)&Bs[(wc * 64 + ni * 16 + frow) * 32 + qoff];
    if (ASPLIT) {
#pragma unroll
      for (int mi = 0; mi < 4; mi++)
        afl[mi] =
            *(const fp16x8*)&As[ALO + (wr * 64 + mi * 16 + frow) * 32 + qoff];
    }

#pragma unroll
    for (int mi = 0; mi < 4; mi++)
#pragma unroll
      for (int ni = 0; ni < 4; ni++) {
        fx4 a = acc[mi][ni];
        a = __builtin_amdgcn_mfma_f32_16x16x32_f16(afh[mi], bbh[ni], a, 0, 0, 0);
        if (ASPLIT)
          a = __builtin_amdgcn_mfma_f32_16x16x32_f16(afl[mi], bbh[ni], a, 0, 0, 0);
        acc[mi][ni] = a;
      }
  }

  // Epilogue. C/D layout: col = lane&15, row = (lane>>4)*4 + reg  [m89/m91]
  const int er = (lane >> 4) * 4;
  const int ec = lane & 15;
  const long long crow = tile_m + wr * 64;
  const long long ccol = tile_n + wc * 64;

#pragma unroll
  for (int mi = 0; mi < 4; mi++)
#pragma unroll
    for (int j = 0; j < 4; j++) {
      const long long r = crow + mi * 16 + er + j;
#pragma unroll
      for (int ni = 0; ni < 4; ni++) {
        const long long cc = ccol + ni * 16 + ec;
        const long long idx = z * sC + r * N + cc;
        const float v = acc[mi][ni][j];
        if (EPI == EPI_F32) {
          ((float*)Cv)[idx] = v;
        } else if (EPI == EPI_F16) {
          ((fp16_t*)Cv)[idx] = (fp16_t)v;
        } else {  // EPI_FUSE
          float u = v + bias[cc];
          u = u > 0.f ? u : 0.f;
          ((float*)Cv)[idx] = resid[r * N + cc] + u;
        }
      }
    }
}

// ---------------------------------------------------------------------------
// Row softmax of s, fully fused: per-row max (diag masked), sum of exp, and
// materialize P = exp(s-m)/l as fp16 IN-PLACE over the s buffer.
// P row r lives in the first half of s row r (stride 4096 fp16 elements =
// 8192 B, same as the fp32 row stride). Safe: each block reads its entire
// row into registers before writing, and only touches its own row.
// One 256-thread block per row.
// ---------------------------------------------------------------------------
__global__ __launch_bounds__(256) void rowstat(
    const float* __restrict__ s, fp16_t* __restrict__ P) {
  __shared__ float red[8];
  const int row = blockIdx.x;
  const int m = row & 2047;  // diagonal position (chunks are whole batches)
  const float4* sr = (const float4*)(s + (long long)row * 2048);
  const int lane = threadIdx.x & 63;
  const int w = threadIdx.x >> 6;
  const int t0 = threadIdx.x * 8;

  const float4 u0 = sr[threadIdx.x * 2];
  const float4 u1 = sr[threadIdx.x * 2 + 1];
  float v[8] = {u0.x, u0.y, u0.z, u0.w, u1.x, u1.y, u1.z, u1.w};

  float mx = -1e30f;
#pragma unroll
  for (int j = 0; j < 8; j++) {
    if (t0 + j == m) v[j] = -1e30f;
    mx = fmaxf(mx, v[j]);
  }
  for (int o = 32; o > 0; o >>= 1) mx = fmaxf(mx, __shfl_down(mx, o, 64));
  if (lane == 0) red[w] = mx;
  __syncthreads();
  mx = fmaxf(fmaxf(red[0], red[1]), fmaxf(red[2], red[3]));

  float e[8];
  float sum = 0.f;
#pragma unroll
  for (int j = 0; j < 8; j++) {
    e[j] = __expf(v[j] - mx);  // diag: expf(-huge) = 0
    sum += e[j];
  }
  for (int o = 32; o > 0; o >>= 1) sum += __shfl_down(sum, o, 64);
  if (lane == 0) red[4 + w] = sum;
  __syncthreads();
  const float il = 1.0f / (red[4] + red[5] + red[6] + red[7]);

  fp16x8 pv;
#pragma unroll
  for (int j = 0; j < 8; j++) pv[j] = (fp16_t)(e[j] * il);
  *(fp16x8*)(P + (long long)row * 4096 + t0) = pv;
}

// ---------------------------------------------------------------------------
// Fused prep: x fp32 -> xh, xl (hi/lo fp16, row-major) + xT (hi, transposed)
// ---------------------------------------------------------------------------
__global__ __launch_bounds__(256) void prep_x(
    const float* __restrict__ x, fp16_t* __restrict__ xh,
    fp16_t* __restrict__ xl, fp16_t* __restrict__ xT) {
  __shared__ fp16_t t[32][33];
  const int b = blockIdx.z;
  const int d0 = blockIdx.x * 32;
  const int s0 = blockIdx.y * 32;
  const float* ib = x + (long long)b * 2048 * 768;
  const int tx = threadIdx.x & 31;
  const int ty = threadIdx.x >> 5;
#pragma unroll
  for (int i = 0; i < 4; i++) {
    const int srow = s0 + ty + i * 8;
    const long long idx = (long long)b * 2048 * 768 + (long long)srow * 768 + d0 + tx;
    const float v = ib[(long long)srow * 768 + d0 + tx];
    const fp16_t h = (fp16_t)v;
    xh[idx] = h;
    xl[idx] = (fp16_t)(v - (float)h);
    t[ty + i * 8][tx] = h;
  }
  __syncthreads();
#pragma unroll
  for (int i = 0; i < 4; i++)
    xT[(long long)b * 768 * 2048 + (long long)(d0 + ty + i * 8) * 2048 + s0 + tx] =
        t[tx][ty + i * 8];
}

// ---------------------------------------------------------------------------
__global__ __launch_bounds__(256) void cast_f32_f16(
    const float* __restrict__ in, fp16_t* __restrict__ out, int n4) {
  const int i = blockIdx.x * 256 + threadIdx.x;
  if (i >= n4) return;
  const float4 v = ((const float4*)in)[i];
  ((fp16x4*)out)[i] =
      (fp16x4){(fp16_t)v.x, (fp16_t)v.y, (fp16_t)v.z, (fp16_t)v.w};
}

// ---------------------------------------------------------------------------
extern "C" void kernel_launch(void* const* d_in, const int* in_sizes, int n_in,
                              void* d_out, int out_size, void* d_ws,
                              size_t ws_size, hipStream_t stream) {
  const float* x  = (const float*)d_in[0];
  const float* W  = (const float*)d_in[1];
  const float* pw = (const float*)d_in[2];
  const float* pb = (const float*)d_in[3];

  const long long S = 2048, D = 768;
  const long long BS = 8 * S;

  // ---- fixed workspace (~103.3 MB) ----
  char* p = (char*)d_ws;
  auto carve = [&](long long bytes) {
    char* q = p;
    p += (bytes + 255) & ~255LL;
    return q;
  };
  fp16_t* xh = (fp16_t*)carve(BS * D * 2);   // x hi           25.2 MB
  fp16_t* xl = (fp16_t*)carve(BS * D * 2);   // x lo (G1 only) 25.2 MB
  fp16_t* xT = (fp16_t*)carve(BS * D * 2);   // x^T (hi)       25.2 MB
  fp16_t* Wx = (fp16_t*)carve(BS * D * 2);   // Wx fp16 / c    25.2 MB
  fp16_t* Wh = (fp16_t*)carve(D * D * 2);    // W fp16          1.2 MB
  fp16_t* ph = (fp16_t*)carve(D * D * 2);    // proj_w fp16     1.2 MB
  fp16_t* cb = Wx;  // c aliases Wx: Wx[batch] dead after GEMM2[batch]
  const long long avail = (long long)ws_size - (long long)(p - (char*)d_ws);

  // ---- prep ----
  prep_x<<<dim3(24, 64, 8), 256, 0, stream>>>(x, xh, xl, xT);
  cast_f32_f16<<<(unsigned)(D * D / 4 / 256), 256, 0, stream>>>(
      W, Wh, (int)(D * D / 4));
  cast_f32_f16<<<(unsigned)(D * D / 4 / 256), 256, 0, stream>>>(
      pw, ph, (int)(D * D / 4));

  // GEMM1 (2-term): Wx = (x_hi + x_lo) @ W^T, fp16 out
  gemm_bt<true, EPI_F16><<<dim3(6, 128, 1), 256, 0, stream>>>(
      xh, xl, Wh, Wx, 768, 768, 768, 0, 0, 0, nullptr, nullptr);

  // ---- attention middle, chunked over whole batches (ws≈268MB -> nb=8) ----
  const long long perb = S * S * 4;  // s fp32 per batch = 16.78 MB
  int nb = (int)(avail / perb);
  if (nb < 1) nb = 1;
  if (nb > 8) nb = 8;
  float* sb = (float*)p;

  for (int c0 = 0; c0 < 8; c0 += nb) {
    const int n = (8 - c0) < nb ? (8 - c0) : nb;
    // GEMM2: s = Wx @ x_hi^T per batch, fp32 out
    gemm_bt<false, EPI_F32><<<dim3(16, 16, n), 256, 0, stream>>>(
        Wx + (long long)c0 * S * D, nullptr, xh + (long long)c0 * S * D,
        sb, 768, 768, 768, S * D, S * D, S * S, nullptr, nullptr);
    // fused row softmax: P = exp(s-m)/l as fp16, in-place (stride 4096)
    rowstat<<<(unsigned)(n * S), 256, 0, stream>>>(sb, (fp16_t*)sb);
    // PV: c = P @ x  ==  P · (xT)^T, plain fp16 GEMM, K = 2048
    gemm_bt<false, EPI_F16><<<dim3(6, 16, n), 256, 0, stream>>>(
        (const fp16_t*)sb, nullptr, xT + (long long)c0 * D * S,
        cb + (long long)c0 * S * D, 2048, 4096, 2048,
        S * S * 2, D * S, S * D, nullptr, nullptr);
  }

  // GEMM4: out = x + relu(c @ proj_w^T + pb), fp32
  gemm_bt<false, EPI_FUSE><<<dim3(6, 128, 1), 256, 0, stream>>>(
      cb, nullptr, ph, (float*)d_out, 768, 768, 768, 0, 0, 0, pb, x);
}

// Round 2
// 404.415 us; speedup vs baseline: 1.0484x; 1.0039x over previous
//
#include <hip/hip_runtime.h>
#include <hip/hip_bf16.h>

typedef _Float16 fp16_t;
typedef __attribute__((ext_vector_type(8))) _Float16 fp16x8;
typedef __attribute__((ext_vector_type(4))) _Float16 fp16x4;
typedef __attribute__((ext_vector_type(4))) float fx4;

#define GLDS(g, l)                                                              \
  __builtin_amdgcn_global_load_lds(                                             \
      (const __attribute__((address_space(1))) void*)(g),                       \
      (__attribute__((address_space(3))) void*)(l), 16, 0, 0)

enum { EPI_F32 = 0, EPI_F16 = 1, EPI_FUSE = 2, EPI_SOFT = 3 };

// ---------------------------------------------------------------------------
// XCD-aware block remap. Requires gridDim.y*gridDim.z divisible by 8.
// ---------------------------------------------------------------------------
__device__ __forceinline__ void xcd_decode(int& bx, int& by, int& bz) {
  const int nx = gridDim.x, ny = gridDim.y;
  const int lid = (int)(blockIdx.x + nx * (blockIdx.y + ny * blockIdx.z));
  const int j = lid & 7, k = lid >> 3;
  bx = k % nx;
  const int s = j + 8 * (k / nx);
  by = s % ny;
  bz = s / ny;
}

// ---------------------------------------------------------------------------
// BT-layout fp16 GEMM: C = A1·B1^T (+ A2·B1^T if ASPLIT)
// A: [M,K] row-major lda, B: [N,K] row-major ldb. Tile 128x128, BK=32, 4 waves.
// EPI_SOFT: tile-local softmax epilogue — masks diagonal, computes per-row
// tile max m_t and exp-sum l_t, stores exp(v-m_t) as fp16, stats to m/l_out.
// ---------------------------------------------------------------------------
template <bool ASPLIT, int EPI>
__global__ __launch_bounds__(256) void gemm_bt(
    const fp16_t* __restrict__ A1, const fp16_t* __restrict__ A2,
    const fp16_t* __restrict__ B1, void* __restrict__ Cv, int K, int lda,
    int ldb, long long sA, long long sB, long long sC,
    const float* __restrict__ bias, const float* __restrict__ resid,
    float* __restrict__ m_out, float* __restrict__ l_out) {
  constexpr int ALO = ASPLIT ? 128 * 32 : 0;
  __shared__ __align__(16) fp16_t As[128 * 32 + ALO];
  __shared__ __align__(16) fp16_t Bs[128 * 32];
  __shared__ float sred[(EPI == EPI_SOFT) ? 256 : 1];
  __shared__ float sfin[(EPI == EPI_SOFT) ? 128 : 1];

  const int tid  = threadIdx.x;
  const int lane = tid & 63;
  const int w    = tid >> 6;
  const int wr   = w >> 1;
  const int wc   = w & 1;

  int bx, by, bz;
  xcd_decode(bx, by, bz);
  const int N = (int)gridDim.x * 128;
  const long long tile_m = (long long)by * 128;
  const long long tile_n = (long long)bx * 128;
  const long long z = bz;
  const long long aoff = z * sA + tile_m * (long long)lda;
  const long long boff = z * sB + tile_n * (long long)ldb;

  fx4 acc[4][4];
#pragma unroll
  for (int i = 0; i < 4; i++)
#pragma unroll
    for (int j = 0; j < 4; j++) acc[i][j] = (fx4){0.f, 0.f, 0.f, 0.f};

  // staging swizzle: LDS slot m holds global chunk (m+(r>>1))&3 of row r
  const int r_l = lane >> 2;
  const int c_l = ((((lane & 3) + ((r_l >> 1) & 3)) & 3) << 3);
  const int frow = lane & 15;
  const int qoff = (((lane >> 4) - ((frow >> 1) & 3)) & 3) << 3;

  const size_t sa0 = (size_t)(w * 16 + r_l) * lda + c_l;
  const size_t sa1 = (size_t)(64 + w * 16 + r_l) * lda + c_l;
  const size_t sb0 = (size_t)(w * 16 + r_l) * ldb + c_l;
  const size_t sb1 = (size_t)(64 + w * 16 + r_l) * ldb + c_l;
  const int ld0 = (w * 16) * 32;
  const int ld1 = (64 + w * 16) * 32;

  for (int kt = 0; kt < K; kt += 32) {
    __syncthreads();
    {
      const fp16_t* gah = A1 + aoff + kt;
      const fp16_t* gbh = B1 + boff + kt;
      GLDS(gah + sa0, &As[ld0]);
      GLDS(gah + sa1, &As[ld1]);
      GLDS(gbh + sb0, &Bs[ld0]);
      GLDS(gbh + sb1, &Bs[ld1]);
      if (ASPLIT) {
        const fp16_t* gal = A2 + aoff + kt;
        GLDS(gal + sa0, &As[ALO + ld0]);
        GLDS(gal + sa1, &As[ALO + ld1]);
      }
    }
    __syncthreads();

    fp16x8 afh[4], bbh[4], afl[4];
#pragma unroll
    for (int mi = 0; mi < 4; mi++)
      afh[mi] = *(const fp16x8*)&As[(wr * 64 + mi * 16 + frow) * 32 + qoff];
#pragma unroll
    for (int ni = 0; ni < 4; ni++)
      bbh[ni] = *(const fp16x8*)&Bs[(wc * 64 + ni * 16 + frow) * 32 + qoff];
    if (ASPLIT) {
#pragma unroll
      for (int mi = 0; mi < 4; mi++)
        afl[mi] =
            *(const fp16x8*)&As[ALO + (wr * 64 + mi * 16 + frow) * 32 + qoff];
    }

#pragma unroll
    for (int mi = 0; mi < 4; mi++)
#pragma unroll
      for (int ni = 0; ni < 4; ni++) {
        fx4 a = acc[mi][ni];
        a = __builtin_amdgcn_mfma_f32_16x16x32_f16(afh[mi], bbh[ni], a, 0, 0, 0);
        if (ASPLIT)
          a = __builtin_amdgcn_mfma_f32_16x16x32_f16(afl[mi], bbh[ni], a, 0, 0, 0);
        acc[mi][ni] = a;
      }
  }

  // Epilogue. C/D layout: col = lane&15, row = (lane>>4)*4 + reg  [m89/m91]
  const int er = (lane >> 4) * 4;
  const int ec = lane & 15;
  const long long crow = tile_m + wr * 64;
  const long long ccol = tile_n + wc * 64;

  if constexpr (EPI == EPI_SOFT) {
    // --- mask diagonal, per-lane row-max over ni ---
    float pm[4][4];
#pragma unroll
    for (int mi = 0; mi < 4; mi++)
#pragma unroll
      for (int j = 0; j < 4; j++) {
        const long long r = crow + mi * 16 + er + j;
        float mx = -1e30f;
#pragma unroll
        for (int ni = 0; ni < 4; ni++) {
          const long long cc = ccol + ni * 16 + ec;
          float v = acc[mi][ni][j];
          if (r == cc) v = -1e30f;
          acc[mi][ni][j] = v;
          mx = fmaxf(mx, v);
        }
        pm[mi][j] = mx;
      }
    // butterfly over the 16-lane group holding this row (xor bits 0..3)
#pragma unroll
    for (int o = 1; o < 16; o <<= 1)
#pragma unroll
      for (int mi = 0; mi < 4; mi++)
#pragma unroll
        for (int j = 0; j < 4; j++)
          pm[mi][j] = fmaxf(pm[mi][j], __shfl_xor(pm[mi][j], o, 64));
    // cross-wave (wc) combine via LDS
    if (ec == 0) {
#pragma unroll
      for (int mi = 0; mi < 4; mi++)
#pragma unroll
        for (int j = 0; j < 4; j++)
          sred[wc * 128 + wr * 64 + mi * 16 + er + j] = pm[mi][j];
    }
    __syncthreads();
    if (tid < 128) sfin[tid] = fmaxf(sred[tid], sred[128 + tid]);
    __syncthreads();
    // --- exp(v - m_tile), per-row sum ---
    float ps[4][4];
#pragma unroll
    for (int mi = 0; mi < 4; mi++)
#pragma unroll
      for (int j = 0; j < 4; j++) {
        const float m = sfin[wr * 64 + mi * 16 + er + j];
        float s = 0.f;
#pragma unroll
        for (int ni = 0; ni < 4; ni++) {
          const float e = __expf(acc[mi][ni][j] - m);  // diag -> 0
          acc[mi][ni][j] = e;
          s += e;
        }
        ps[mi][j] = s;
      }
#pragma unroll
    for (int o = 1; o < 16; o <<= 1)
#pragma unroll
      for (int mi = 0; mi < 4; mi++)
#pragma unroll
        for (int j = 0; j < 4; j++)
          ps[mi][j] += __shfl_xor(ps[mi][j], o, 64);
    __syncthreads();  // sred free again
    if (ec == 0) {
#pragma unroll
      for (int mi = 0; mi < 4; mi++)
#pragma unroll
        for (int j = 0; j < 4; j++)
          sred[wc * 128 + wr * 64 + mi * 16 + er + j] = ps[mi][j];
    }
    __syncthreads();
    if (tid < 128) {
      const long long si = (z * 16 + bx) * 2048 + tile_m + tid;
      m_out[si] = sfin[tid];
      l_out[si] = sred[tid] + sred[128 + tid];
    }
    // --- store P' = exp(v - m_tile) as fp16 ---
#pragma unroll
    for (int mi = 0; mi < 4; mi++)
#pragma unroll
      for (int j = 0; j < 4; j++) {
        const long long r = crow + mi * 16 + er + j;
#pragma unroll
        for (int ni = 0; ni < 4; ni++) {
          const long long cc = ccol + ni * 16 + ec;
          ((fp16_t*)Cv)[z * sC + r * N + cc] = (fp16_t)acc[mi][ni][j];
        }
      }
  } else {
#pragma unroll
    for (int mi = 0; mi < 4; mi++)
#pragma unroll
      for (int j = 0; j < 4; j++) {
        const long long r = crow + mi * 16 + er + j;
#pragma unroll
        for (int ni = 0; ni < 4; ni++) {
          const long long cc = ccol + ni * 16 + ec;
          const long long idx = z * sC + r * N + cc;
          const float v = acc[mi][ni][j];
          if (EPI == EPI_F32) {
            ((float*)Cv)[idx] = v;
          } else if (EPI == EPI_F16) {
            ((fp16_t*)Cv)[idx] = (fp16_t)v;
          } else {  // EPI_FUSE
            float u = v + bias[cc];
            u = u > 0.f ? u : 0.f;
            ((float*)Cv)[idx] = resid[r * N + cc] + u;
          }
        }
      }
  }
}

// ---------------------------------------------------------------------------
// Merge per-tile softmax stats: for each (z,row):
//   m = max_t m_t ; l = sum_t l_t * exp(m_t - m) ; scale[t] = exp(m_t - m)/l
// Layout of all stat arrays: [(z*16 + t)*2048 + row]  (coalesced over rows).
// ---------------------------------------------------------------------------
__global__ __launch_bounds__(256) void softmerge(
    const float* __restrict__ mstat, const float* __restrict__ lstat,
    float* __restrict__ scale) {
  const int gr = blockIdx.x * 256 + threadIdx.x;  // [0, 8*2048)
  const int z = gr >> 11, row = gr & 2047;
  const long long base = ((long long)z * 16) * 2048 + row;
  float mv[16], lv[16];
  float m = -1e30f;
#pragma unroll
  for (int t = 0; t < 16; t++) {
    mv[t] = mstat[base + t * 2048];
    m = fmaxf(m, mv[t]);
  }
  float l = 0.f;
#pragma unroll
  for (int t = 0; t < 16; t++) {
    lv[t] = lstat[base + t * 2048];
    l += lv[t] * __expf(mv[t] - m);
  }
  const float il = 1.0f / l;
#pragma unroll
  for (int t = 0; t < 16; t++) scale[base + t * 2048] = __expf(mv[t] - m) * il;
}

// ---------------------------------------------------------------------------
// PV GEMM: c[m,d] = sum_t scale[m, t/128] * P'[m,t] * xT[d,t]
// A side reg-staged from fp16 P' with one packed fp16 scale-mul, written into
// the swizzled LDS layout; B side GLDS as usual. Grid (6, 16, 8). K = 2048.
// ---------------------------------------------------------------------------
__global__ __launch_bounds__(256) void gemm_pv(
    const fp16_t* __restrict__ P, const float* __restrict__ scale,
    const fp16_t* __restrict__ Bx, fp16_t* __restrict__ C) {
  __shared__ __align__(16) fp16_t As[128 * 32];
  __shared__ __align__(16) fp16_t Bs[128 * 32];

  const int tid  = threadIdx.x;
  const int lane = tid & 63;
  const int w    = tid >> 6;
  const int wr   = w >> 1;
  const int wc   = w & 1;

  int bx, by, bz;
  xcd_decode(bx, by, bz);
  const long long tile_m = (long long)by * 128;
  const long long tile_n = (long long)bx * 128;
  const long long z = bz;

  fx4 acc[4][4];
#pragma unroll
  for (int i = 0; i < 4; i++)
#pragma unroll
    for (int j = 0; j < 4; j++) acc[i][j] = (fx4){0.f, 0.f, 0.f, 0.f};

  // B staging (GLDS, swizzled), ldb = 2048
  const int r_l = lane >> 2;
  const int c_l = ((((lane & 3) + ((r_l >> 1) & 3)) & 3) << 3);
  const int frow = lane & 15;
  const int qoff = (((lane >> 4) - ((frow >> 1) & 3)) & 3) << 3;
  const size_t sb0 = (size_t)(w * 16 + r_l) * 2048 + c_l;
  const size_t sb1 = (size_t)(64 + w * 16 + r_l) * 2048 + c_l;
  const int ld0 = (w * 16) * 32;
  const int ld1 = (64 + w * 16) * 32;
  const fp16_t* B = Bx + z * (768LL * 2048) + tile_n * 2048;

  // A side: thread -> (row r, half hh); covers 16 fp16 = chunks 2hh, 2hh+1
  const int r = tid >> 1, hh = tid & 1;
  const int gm = (int)tile_m + r;  // row within batch
  const fp16_t* prow = P + z * (2048LL * 2048) + (long long)gm * 2048 + hh * 16;
  const float* srow = scale + (long long)z * 16 * 2048 + gm;
  // global chunk q of row r lives at LDS slot (q-(r>>1))&3
  const int slot0 = ((2 * hh + 0) - ((r >> 1) & 3)) & 3;
  const int slot1 = ((2 * hh + 1) - ((r >> 1) & 3)) & 3;
  fp16_t* const wp0 = &As[r * 32 + slot0 * 8];
  fp16_t* const wp1 = &As[r * 32 + slot1 * 8];

  for (int kt0 = 0; kt0 < 2048; kt0 += 128) {
    const fp16_t sh = (fp16_t)srow[(kt0 >> 7) * 2048];
#pragma unroll
    for (int ki = 0; ki < 4; ki++) {
      const int kt = kt0 + ki * 32;
      fp16x8 c0 = *(const fp16x8*)(prow + kt);
      fp16x8 c1 = *(const fp16x8*)(prow + kt + 8);
      c0 *= sh;
      c1 *= sh;
      __syncthreads();  // previous iter's fragment reads done
      *(fp16x8*)wp0 = c0;
      *(fp16x8*)wp1 = c1;
      GLDS(B + kt + sb0, &Bs[ld0]);
      GLDS(B + kt + sb1, &Bs[ld1]);
      __syncthreads();  // drains lgkm (ds_write) + vm (GLDS)

      fp16x8 af[4], bb[4];
#pragma unroll
      for (int mi = 0; mi < 4; mi++)
        af[mi] = *(const fp16x8*)&As[(wr * 64 + mi * 16 + frow) * 32 + qoff];
#pragma unroll
      for (int ni = 0; ni < 4; ni++)
        bb[ni] = *(const fp16x8*)&Bs[(wc * 64 + ni * 16 + frow) * 32 + qoff];
#pragma unroll
      for (int mi = 0; mi < 4; mi++)
#pragma unroll
        for (int ni = 0; ni < 4; ni++)
          acc[mi][ni] = __builtin_amdgcn_mfma_f32_16x16x32_f16(
              af[mi], bb[ni], acc[mi][ni], 0, 0, 0);
    }
  }

  const int er = (lane >> 4) * 4;
  const int ec = lane & 15;
  const long long crow = tile_m + wr * 64;
  const long long ccol = tile_n + wc * 64;
  fp16_t* Cz = C + z * (2048LL * 768);
#pragma unroll
  for (int mi = 0; mi < 4; mi++)
#pragma unroll
    for (int j = 0; j < 4; j++) {
      const long long rr = crow + mi * 16 + er + j;
#pragma unroll
      for (int ni = 0; ni < 4; ni++)
        Cz[rr * 768 + ccol + ni * 16 + ec] = (fp16_t)acc[mi][ni][j];
    }
}

// ---------------------------------------------------------------------------
// Fused prep: x fp32 -> xh, xl (hi/lo fp16, row-major) + xT (hi, transposed)
// ---------------------------------------------------------------------------
__global__ __launch_bounds__(256) void prep_x(
    const float* __restrict__ x, fp16_t* __restrict__ xh,
    fp16_t* __restrict__ xl, fp16_t* __restrict__ xT) {
  __shared__ fp16_t t[32][33];
  const int b = blockIdx.z;
  const int d0 = blockIdx.x * 32;
  const int s0 = blockIdx.y * 32;
  const float* ib = x + (long long)b * 2048 * 768;
  const int tx = threadIdx.x & 31;
  const int ty = threadIdx.x >> 5;
#pragma unroll
  for (int i = 0; i < 4; i++) {
    const int srow = s0 + ty + i * 8;
    const long long idx = (long long)b * 2048 * 768 + (long long)srow * 768 + d0 + tx;
    const float v = ib[(long long)srow * 768 + d0 + tx];
    const fp16_t h = (fp16_t)v;
    xh[idx] = h;
    xl[idx] = (fp16_t)(v - (float)h);
    t[ty + i * 8][tx] = h;
  }
  __syncthreads();
#pragma unroll
  for (int i = 0; i < 4; i++)
    xT[(long long)b * 768 * 2048 + (long long)(d0 + ty + i * 8) * 2048 + s0 + tx] =
        t[tx][ty + i * 8];
}

// ---------------------------------------------------------------------------
__global__ __launch_bounds__(256) void cast_f32_f16(
    const float* __restrict__ in, fp16_t* __restrict__ out, int n4) {
  const int i = blockIdx.x * 256 + threadIdx.x;
  if (i >= n4) return;
  const float4 v = ((const float4*)in)[i];
  ((fp16x4*)out)[i] =
      (fp16x4){(fp16_t)v.x, (fp16_t)v.y, (fp16_t)v.z, (fp16_t)v.w};
}

// ---------------------------------------------------------------------------
extern "C" void kernel_launch(void* const* d_in, const int* in_sizes, int n_in,
                              void* d_out, int out_size, void* d_ws,
                              size_t ws_size, hipStream_t stream) {
  const float* x  = (const float*)d_in[0];
  const float* W  = (const float*)d_in[1];
  const float* pw = (const float*)d_in[2];
  const float* pb = (const float*)d_in[3];

  const long long S = 2048, D = 768;
  const long long BS = 8 * S;

  // ---- workspace (~174 MB) ----
  char* p = (char*)d_ws;
  auto carve = [&](long long bytes) {
    char* q = p;
    p += (bytes + 255) & ~255LL;
    return q;
  };
  fp16_t* xh = (fp16_t*)carve(BS * D * 2);       // x hi           25.2 MB
  fp16_t* xl = (fp16_t*)carve(BS * D * 2);       // x lo (G1 only) 25.2 MB
  fp16_t* xT = (fp16_t*)carve(BS * D * 2);       // x^T (hi)       25.2 MB
  fp16_t* Wx = (fp16_t*)carve(BS * D * 2);       // Wx fp16 / c    25.2 MB
  fp16_t* Wh = (fp16_t*)carve(D * D * 2);        // W fp16          1.2 MB
  fp16_t* ph = (fp16_t*)carve(D * D * 2);        // proj_w fp16     1.2 MB
  float*  mstat = (float*)carve(BS * 16 * 4);    // per-tile max    1.0 MB
  float*  lstat = (float*)carve(BS * 16 * 4);    // per-tile sum    1.0 MB
  float*  scale = (float*)carve(BS * 16 * 4);    // merged scales   1.0 MB
  fp16_t* Ps = (fp16_t*)carve(8 * S * S * 2);    // P' fp16        67.1 MB
  fp16_t* cb = Wx;  // c aliases Wx: Wx fully consumed by GEMM2 before PV

  // ---- prep ----
  prep_x<<<dim3(24, 64, 8), 256, 0, stream>>>(x, xh, xl, xT);
  cast_f32_f16<<<(unsigned)(D * D / 4 / 256), 256, 0, stream>>>(
      W, Wh, (int)(D * D / 4));
  cast_f32_f16<<<(unsigned)(D * D / 4 / 256), 256, 0, stream>>>(
      pw, ph, (int)(D * D / 4));

  // GEMM1 (2-term): Wx = (x_hi + x_lo) @ W^T, fp16 out
  gemm_bt<true, EPI_F16><<<dim3(6, 128, 1), 256, 0, stream>>>(
      xh, xl, Wh, Wx, 768, 768, 768, 0, 0, 0, nullptr, nullptr, nullptr,
      nullptr);

  // GEMM2 + tile-softmax: P' = exp(s - m_tile) fp16, stats m_t/l_t
  gemm_bt<false, EPI_SOFT><<<dim3(16, 16, 8), 256, 0, stream>>>(
      Wx, nullptr, xh, Ps, 768, 768, 768, S * D, S * D, S * S, nullptr,
      nullptr, mstat, lstat);

  // merge per-tile stats -> scale[z][t][row] = exp(m_t - m)/l
  softmerge<<<(unsigned)(BS / 256), 256, 0, stream>>>(mstat, lstat, scale);

  // PV: c = (scale ⊙ P') @ x  ==  A · (xT)^T, K = 2048
  gemm_pv<<<dim3(6, 16, 8), 256, 0, stream>>>(Ps, scale, xT, cb);

  // GEMM4: out = x + relu(c @ proj_w^T + pb), fp32
  gemm_bt<false, EPI_FUSE><<<dim3(6, 128, 1), 256, 0, stream>>>(
      cb, nullptr, ph, (float*)d_out, 768, 768, 768, 0, 0, 0, pb, x, nullptr,
      nullptr);
}

// Round 3
// 380.137 us; speedup vs baseline: 1.1154x; 1.0639x over previous
//
#include <hip/hip_runtime.h>
#include <hip/hip_bf16.h>

typedef _Float16 fp16_t;
typedef __attribute__((ext_vector_type(8))) _Float16 fp16x8;
typedef __attribute__((ext_vector_type(4))) _Float16 fp16x4;
typedef __attribute__((ext_vector_type(4))) float fx4;

#define GLDS(g, l)                                                              \
  __builtin_amdgcn_global_load_lds(                                             \
      (const __attribute__((address_space(1))) void*)(g),                       \
      (__attribute__((address_space(3))) void*)(l), 16, 0, 0)

enum { EPI_F32 = 0, EPI_F16 = 1, EPI_FUSE = 2, EPI_SOFT = 3 };

// ---------------------------------------------------------------------------
// XCD-aware block remap. Requires gridDim.y*gridDim.z divisible by 8.
// ---------------------------------------------------------------------------
__device__ __forceinline__ void xcd_decode(int& bx, int& by, int& bz) {
  const int nx = gridDim.x, ny = gridDim.y;
  const int lid = (int)(blockIdx.x + nx * (blockIdx.y + ny * blockIdx.z));
  const int j = lid & 7, k = lid >> 3;
  bx = k % nx;
  const int s = j + 8 * (k / nx);
  by = s % ny;
  bz = s / ny;
}

// ---------------------------------------------------------------------------
// BT-layout fp16 GEMM: C = A1·B1^T (+ A2·B1^T if ASPLIT)
// A: [M,K] row-major lda, B: [N,K] row-major ldb. Tile 128x128, 4 waves.
// Twin-buffer BK=64: two 32-wide LDS buffers staged per barrier pair —
// halves barrier count, 8 GLDS in flight per drain. K must be % 64.
// EPI_SOFT: tile-local softmax epilogue, register-lean (per-row streaming).
// ---------------------------------------------------------------------------
template <bool ASPLIT, int EPI>
__global__ __launch_bounds__(256) void gemm_bt(
    const fp16_t* __restrict__ A1, const fp16_t* __restrict__ A2,
    const fp16_t* __restrict__ B1, void* __restrict__ Cv, int K, int lda,
    int ldb, long long sA, long long sB, long long sC,
    const float* __restrict__ bias, const float* __restrict__ resid,
    float* __restrict__ m_out, float* __restrict__ l_out) {
  constexpr int ALO = ASPLIT ? 128 * 32 : 0;
  __shared__ __align__(16) fp16_t As[2][128 * 32 + ALO];
  __shared__ __align__(16) fp16_t Bs[2][128 * 32];
  __shared__ float smax[(EPI == EPI_SOFT) ? 256 : 1];
  __shared__ float ssum[(EPI == EPI_SOFT) ? 256 : 1];

  const int tid  = threadIdx.x;
  const int lane = tid & 63;
  const int w    = tid >> 6;
  const int wr   = w >> 1;
  const int wc   = w & 1;

  int bx, by, bz;
  xcd_decode(bx, by, bz);
  const int N = (int)gridDim.x * 128;
  const long long tile_m = (long long)by * 128;
  const long long tile_n = (long long)bx * 128;
  const long long z = bz;
  const long long aoff = z * sA + tile_m * (long long)lda;
  const long long boff = z * sB + tile_n * (long long)ldb;

  fx4 acc[4][4];
#pragma unroll
  for (int i = 0; i < 4; i++)
#pragma unroll
    for (int j = 0; j < 4; j++) acc[i][j] = (fx4){0.f, 0.f, 0.f, 0.f};

  // staging swizzle: LDS slot m holds global chunk (m+(r>>1))&3 of row r
  const int r_l = lane >> 2;
  const int c_l = ((((lane & 3) + ((r_l >> 1) & 3)) & 3) << 3);
  const int frow = lane & 15;
  const int qoff = (((lane >> 4) - ((frow >> 1) & 3)) & 3) << 3;

  const size_t sa0 = (size_t)(w * 16 + r_l) * lda + c_l;
  const size_t sa1 = (size_t)(64 + w * 16 + r_l) * lda + c_l;
  const size_t sb0 = (size_t)(w * 16 + r_l) * ldb + c_l;
  const size_t sb1 = (size_t)(64 + w * 16 + r_l) * ldb + c_l;
  const int ld0 = (w * 16) * 32;
  const int ld1 = (64 + w * 16) * 32;

  for (int kt = 0; kt < K; kt += 64) {
    __syncthreads();
#pragma unroll
    for (int h = 0; h < 2; h++) {
      const fp16_t* gah = A1 + aoff + kt + h * 32;
      const fp16_t* gbh = B1 + boff + kt + h * 32;
      GLDS(gah + sa0, &As[h][ld0]);
      GLDS(gah + sa1, &As[h][ld1]);
      GLDS(gbh + sb0, &Bs[h][ld0]);
      GLDS(gbh + sb1, &Bs[h][ld1]);
      if (ASPLIT) {
        const fp16_t* gal = A2 + aoff + kt + h * 32;
        GLDS(gal + sa0, &As[h][ALO + ld0]);
        GLDS(gal + sa1, &As[h][ALO + ld1]);
      }
    }
    __syncthreads();

#pragma unroll
    for (int h = 0; h < 2; h++) {
      fp16x8 afh[4], bbh[4], afl[4];
#pragma unroll
      for (int mi = 0; mi < 4; mi++)
        afh[mi] = *(const fp16x8*)&As[h][(wr * 64 + mi * 16 + frow) * 32 + qoff];
#pragma unroll
      for (int ni = 0; ni < 4; ni++)
        bbh[ni] = *(const fp16x8*)&Bs[h][(wc * 64 + ni * 16 + frow) * 32 + qoff];
      if (ASPLIT) {
#pragma unroll
        for (int mi = 0; mi < 4; mi++)
          afl[mi] =
              *(const fp16x8*)&As[h][ALO + (wr * 64 + mi * 16 + frow) * 32 + qoff];
      }
#pragma unroll
      for (int mi = 0; mi < 4; mi++)
#pragma unroll
        for (int ni = 0; ni < 4; ni++) {
          fx4 a = acc[mi][ni];
          a = __builtin_amdgcn_mfma_f32_16x16x32_f16(afh[mi], bbh[ni], a, 0, 0, 0);
          if (ASPLIT)
            a = __builtin_amdgcn_mfma_f32_16x16x32_f16(afl[mi], bbh[ni], a, 0, 0, 0);
          acc[mi][ni] = a;
        }
    }
  }

  // Epilogue. C/D layout: col = lane&15, row = (lane>>4)*4 + reg  [m89/m91]
  const int er = (lane >> 4) * 4;
  const int ec = lane & 15;
  const long long crow = tile_m + wr * 64;
  const long long ccol = tile_n + wc * 64;

  if constexpr (EPI == EPI_SOFT) {
    // pass 1: mask diagonal + per-row max (streaming, no arrays)
#pragma unroll
    for (int mi = 0; mi < 4; mi++)
#pragma unroll
      for (int j = 0; j < 4; j++) {
        const long long r = crow + mi * 16 + er + j;
        float mx = -1e30f;
#pragma unroll
        for (int ni = 0; ni < 4; ni++) {
          const long long cc = ccol + ni * 16 + ec;
          float v = acc[mi][ni][j];
          if (r == cc) v = -1e30f;
          acc[mi][ni][j] = v;
          mx = fmaxf(mx, v);
        }
#pragma unroll
        for (int o = 1; o < 16; o <<= 1) mx = fmaxf(mx, __shfl_xor(mx, o, 64));
        if (ec == 0) smax[wc * 128 + wr * 64 + mi * 16 + er + j] = mx;
      }
    __syncthreads();
    // pass 2: exp + per-row sum + P' store (streaming)
#pragma unroll
    for (int mi = 0; mi < 4; mi++)
#pragma unroll
      for (int j = 0; j < 4; j++) {
        const int rid = wr * 64 + mi * 16 + er + j;
        const float m = fmaxf(smax[rid], smax[128 + rid]);
        const long long r = crow + mi * 16 + er + j;
        float s = 0.f;
#pragma unroll
        for (int ni = 0; ni < 4; ni++) {
          const float e = __expf(acc[mi][ni][j] - m);  // diag -> 0
          s += e;
          ((fp16_t*)Cv)[z * sC + r * N + (ccol + ni * 16 + ec)] = (fp16_t)e;
        }
#pragma unroll
        for (int o = 1; o < 16; o <<= 1) s += __shfl_xor(s, o, 64);
        if (ec == 0) ssum[wc * 128 + rid] = s;
      }
    __syncthreads();
    if (tid < 128) {
      const long long si = (z * 16 + bx) * 2048 + tile_m + tid;
      m_out[si] = fmaxf(smax[tid], smax[128 + tid]);
      l_out[si] = ssum[tid] + ssum[128 + tid];
    }
  } else {
#pragma unroll
    for (int mi = 0; mi < 4; mi++)
#pragma unroll
      for (int j = 0; j < 4; j++) {
        const long long r = crow + mi * 16 + er + j;
#pragma unroll
        for (int ni = 0; ni < 4; ni++) {
          const long long cc = ccol + ni * 16 + ec;
          const long long idx = z * sC + r * N + cc;
          const float v = acc[mi][ni][j];
          if (EPI == EPI_F32) {
            ((float*)Cv)[idx] = v;
          } else if (EPI == EPI_F16) {
            ((fp16_t*)Cv)[idx] = (fp16_t)v;
          } else {  // EPI_FUSE
            float u = v + bias[cc];
            u = u > 0.f ? u : 0.f;
            ((float*)Cv)[idx] = resid[r * N + cc] + u;
          }
        }
      }
  }
}

// ---------------------------------------------------------------------------
// PV GEMM: c[m,d] = sum_t scale[m, t/128] * P'[m,t] * xT[d,t]
// Prologue merges per-tile softmax stats into LDS scale table (softmerge
// fused). A side reg-staged from fp16 P' with one packed fp16 scale-mul;
// B side GLDS. Twin-buffer BK=64. Grid (6, 16, 8). K = 2048.
// ---------------------------------------------------------------------------
__global__ __launch_bounds__(256) void gemm_pv(
    const fp16_t* __restrict__ P, const float* __restrict__ mstat,
    const float* __restrict__ lstat, const fp16_t* __restrict__ Bx,
    fp16_t* __restrict__ C) {
  __shared__ __align__(16) fp16_t As[2][128 * 32];
  __shared__ __align__(16) fp16_t Bs[2][128 * 32];
  __shared__ float sc[16][128];

  const int tid  = threadIdx.x;
  const int lane = tid & 63;
  const int w    = tid >> 6;
  const int wr   = w >> 1;
  const int wc   = w & 1;

  int bx, by, bz;
  xcd_decode(bx, by, bz);
  const long long tile_m = (long long)by * 128;
  const long long tile_n = (long long)bx * 128;
  const long long z = bz;

  // fused softmerge: scale[t][row] = exp(m_t - m) / l  for this block's rows
  if (tid < 128) {
    const long long base = z * 16 * 2048 + tile_m + tid;
    float mv[16];
    float m = -1e30f;
#pragma unroll
    for (int t = 0; t < 16; t++) {
      mv[t] = mstat[base + t * 2048];
      m = fmaxf(m, mv[t]);
    }
    float l = 0.f;
#pragma unroll
    for (int t = 0; t < 16; t++) l += lstat[base + t * 2048] * __expf(mv[t] - m);
    const float il = 1.0f / l;
#pragma unroll
    for (int t = 0; t < 16; t++) sc[t][tid] = __expf(mv[t] - m) * il;
  }

  fx4 acc[4][4];
#pragma unroll
  for (int i = 0; i < 4; i++)
#pragma unroll
    for (int j = 0; j < 4; j++) acc[i][j] = (fx4){0.f, 0.f, 0.f, 0.f};

  // B staging (GLDS, swizzled), ldb = 2048
  const int r_l = lane >> 2;
  const int c_l = ((((lane & 3) + ((r_l >> 1) & 3)) & 3) << 3);
  const int frow = lane & 15;
  const int qoff = (((lane >> 4) - ((frow >> 1) & 3)) & 3) << 3;
  const size_t sb0 = (size_t)(w * 16 + r_l) * 2048 + c_l;
  const size_t sb1 = (size_t)(64 + w * 16 + r_l) * 2048 + c_l;
  const int ld0 = (w * 16) * 32;
  const int ld1 = (64 + w * 16) * 32;
  const fp16_t* B = Bx + z * (768LL * 2048) + tile_n * 2048;

  // A side: thread -> (row r, half hh); covers 16 fp16 = chunks 2hh, 2hh+1
  const int r = tid >> 1, hh = tid & 1;
  const int gm = (int)tile_m + r;  // row within batch
  const fp16_t* prow = P + z * (2048LL * 2048) + (long long)gm * 2048 + hh * 16;
  // global chunk q of row r lives at LDS slot (q-(r>>1))&3
  const int slot0 = ((2 * hh + 0) - ((r >> 1) & 3)) & 3;
  const int slot1 = ((2 * hh + 1) - ((r >> 1) & 3)) & 3;
  const int wp0 = r * 32 + slot0 * 8;
  const int wp1 = r * 32 + slot1 * 8;

  __syncthreads();  // sc table ready

  for (int kt0 = 0; kt0 < 2048; kt0 += 128) {
    const fp16_t sh = (fp16_t)sc[kt0 >> 7][r];
#pragma unroll
    for (int kk = 0; kk < 2; kk++) {
      const int kt = kt0 + kk * 64;
      fp16x8 v0[2], v1[2];
#pragma unroll
      for (int h = 0; h < 2; h++) {
        v0[h] = *(const fp16x8*)(prow + kt + h * 32);
        v1[h] = *(const fp16x8*)(prow + kt + h * 32 + 8);
        v0[h] *= sh;
        v1[h] *= sh;
      }
      __syncthreads();  // previous iter's fragment reads done
#pragma unroll
      for (int h = 0; h < 2; h++) {
        *(fp16x8*)&As[h][wp0] = v0[h];
        *(fp16x8*)&As[h][wp1] = v1[h];
        GLDS(B + kt + h * 32 + sb0, &Bs[h][ld0]);
        GLDS(B + kt + h * 32 + sb1, &Bs[h][ld1]);
      }
      __syncthreads();  // drains lgkm (ds_write) + vm (GLDS)

#pragma unroll
      for (int h = 0; h < 2; h++) {
        fp16x8 af[4], bb[4];
#pragma unroll
        for (int mi = 0; mi < 4; mi++)
          af[mi] = *(const fp16x8*)&As[h][(wr * 64 + mi * 16 + frow) * 32 + qoff];
#pragma unroll
        for (int ni = 0; ni < 4; ni++)
          bb[ni] = *(const fp16x8*)&Bs[h][(wc * 64 + ni * 16 + frow) * 32 + qoff];
#pragma unroll
        for (int mi = 0; mi < 4; mi++)
#pragma unroll
          for (int ni = 0; ni < 4; ni++)
            acc[mi][ni] = __builtin_amdgcn_mfma_f32_16x16x32_f16(
                af[mi], bb[ni], acc[mi][ni], 0, 0, 0);
      }
    }
  }

  const int er = (lane >> 4) * 4;
  const int ec = lane & 15;
  const long long crow = tile_m + wr * 64;
  const long long ccol = tile_n + wc * 64;
  fp16_t* Cz = C + z * (2048LL * 768);
#pragma unroll
  for (int mi = 0; mi < 4; mi++)
#pragma unroll
    for (int j = 0; j < 4; j++) {
      const long long rr = crow + mi * 16 + er + j;
#pragma unroll
      for (int ni = 0; ni < 4; ni++)
        Cz[rr * 768 + ccol + ni * 16 + ec] = (fp16_t)acc[mi][ni][j];
    }
}

// ---------------------------------------------------------------------------
// Fused prep: x fp32 -> xh, xl (hi/lo fp16, row-major) + xT (hi, transposed)
// ---------------------------------------------------------------------------
__global__ __launch_bounds__(256) void prep_x(
    const float* __restrict__ x, fp16_t* __restrict__ xh,
    fp16_t* __restrict__ xl, fp16_t* __restrict__ xT) {
  __shared__ fp16_t t[32][33];
  const int b = blockIdx.z;
  const int d0 = blockIdx.x * 32;
  const int s0 = blockIdx.y * 32;
  const float* ib = x + (long long)b * 2048 * 768;
  const int tx = threadIdx.x & 31;
  const int ty = threadIdx.x >> 5;
#pragma unroll
  for (int i = 0; i < 4; i++) {
    const int srow = s0 + ty + i * 8;
    const long long idx = (long long)b * 2048 * 768 + (long long)srow * 768 + d0 + tx;
    const float v = ib[(long long)srow * 768 + d0 + tx];
    const fp16_t h = (fp16_t)v;
    xh[idx] = h;
    xl[idx] = (fp16_t)(v - (float)h);
    t[ty + i * 8][tx] = h;
  }
  __syncthreads();
#pragma unroll
  for (int i = 0; i < 4; i++)
    xT[(long long)b * 768 * 2048 + (long long)(d0 + ty + i * 8) * 2048 + s0 + tx] =
        t[tx][ty + i * 8];
}

// ---------------------------------------------------------------------------
// Both weight casts in one launch: blockIdx.y selects the tensor.
// ---------------------------------------------------------------------------
__global__ __launch_bounds__(256) void cast2_f32_f16(
    const float* __restrict__ a, const float* __restrict__ b,
    fp16_t* __restrict__ oa, fp16_t* __restrict__ ob, int n4) {
  const int i = blockIdx.x * 256 + threadIdx.x;
  if (i >= n4) return;
  const float* in = blockIdx.y == 0 ? a : b;
  fp16_t* out = blockIdx.y == 0 ? oa : ob;
  const float4 v = ((const float4*)in)[i];
  ((fp16x4*)out)[i] =
      (fp16x4){(fp16_t)v.x, (fp16_t)v.y, (fp16_t)v.z, (fp16_t)v.w};
}

// ---------------------------------------------------------------------------
extern "C" void kernel_launch(void* const* d_in, const int* in_sizes, int n_in,
                              void* d_out, int out_size, void* d_ws,
                              size_t ws_size, hipStream_t stream) {
  const float* x  = (const float*)d_in[0];
  const float* W  = (const float*)d_in[1];
  const float* pw = (const float*)d_in[2];
  const float* pb = (const float*)d_in[3];

  const long long S = 2048, D = 768;
  const long long BS = 8 * S;

  // ---- workspace (~171 MB) ----
  char* p = (char*)d_ws;
  auto carve = [&](long long bytes) {
    char* q = p;
    p += (bytes + 255) & ~255LL;
    return q;
  };
  fp16_t* xh = (fp16_t*)carve(BS * D * 2);       // x hi           25.2 MB
  fp16_t* xl = (fp16_t*)carve(BS * D * 2);       // x lo (G1 only) 25.2 MB
  fp16_t* xT = (fp16_t*)carve(BS * D * 2);       // x^T (hi)       25.2 MB
  fp16_t* Wx = (fp16_t*)carve(BS * D * 2);       // Wx fp16 / c    25.2 MB
  fp16_t* Wh = (fp16_t*)carve(D * D * 2);        // W fp16          1.2 MB
  fp16_t* ph = (fp16_t*)carve(D * D * 2);        // proj_w fp16     1.2 MB
  float*  mstat = (float*)carve(BS * 16 * 4);    // per-tile max    1.0 MB
  float*  lstat = (float*)carve(BS * 16 * 4);    // per-tile sum    1.0 MB
  fp16_t* Ps = (fp16_t*)carve(8 * S * S * 2);    // P' fp16        67.1 MB
  fp16_t* cb = Wx;  // c aliases Wx: Wx fully consumed by GEMM2 before PV

  // ---- prep ----
  prep_x<<<dim3(24, 64, 8), 256, 0, stream>>>(x, xh, xl, xT);
  cast2_f32_f16<<<dim3((unsigned)(D * D / 4 / 256), 2), 256, 0, stream>>>(
      W, pw, Wh, ph, (int)(D * D / 4));

  // GEMM1 (2-term): Wx = (x_hi + x_lo) @ W^T, fp16 out
  gemm_bt<true, EPI_F16><<<dim3(6, 128, 1), 256, 0, stream>>>(
      xh, xl, Wh, Wx, 768, 768, 768, 0, 0, 0, nullptr, nullptr, nullptr,
      nullptr);

  // GEMM2 + tile-softmax: P' = exp(s - m_tile) fp16, stats m_t/l_t
  gemm_bt<false, EPI_SOFT><<<dim3(16, 16, 8), 256, 0, stream>>>(
      Wx, nullptr, xh, Ps, 768, 768, 768, S * D, S * D, S * S, nullptr,
      nullptr, mstat, lstat);

  // PV: c = (merged-scale ⊙ P') @ x  ==  A · (xT)^T, K = 2048
  gemm_pv<<<dim3(6, 16, 8), 256, 0, stream>>>(Ps, mstat, lstat, xT, cb);

  // GEMM4: out = x + relu(c @ proj_w^T + pb), fp32
  gemm_bt<false, EPI_FUSE><<<dim3(6, 128, 1), 256, 0, stream>>>(
      cb, nullptr, ph, (float*)d_out, 768, 768, 768, 0, 0, 0, pb, x, nullptr,
      nullptr);
}

// Round 4
// 364.732 us; speedup vs baseline: 1.1625x; 1.0422x over previous
//
#include <hip/hip_runtime.h>
#include <hip/hip_bf16.h>

typedef _Float16 fp16_t;
typedef __attribute__((ext_vector_type(8))) _Float16 fp16x8;
typedef __attribute__((ext_vector_type(4))) _Float16 fp16x4;
typedef __attribute__((ext_vector_type(4))) float fx4;

#define GLDS(g, l)                                                              \
  __builtin_amdgcn_global_load_lds(                                             \
      (const __attribute__((address_space(1))) void*)(g),                       \
      (__attribute__((address_space(3))) void*)(l), 16, 0, 0)

enum { EPI_F32 = 0, EPI_F16 = 1, EPI_FUSE = 2, EPI_SOFT = 3 };

// ---------------------------------------------------------------------------
// XCD-aware block remap. Requires gridDim.y*gridDim.z divisible by 8.
// ---------------------------------------------------------------------------
__device__ __forceinline__ void xcd_decode(int& bx, int& by, int& bz) {
  const int nx = gridDim.x, ny = gridDim.y;
  const int lid = (int)(blockIdx.x + nx * (blockIdx.y + ny * blockIdx.z));
  const int j = lid & 7, k = lid >> 3;
  bx = k % nx;
  const int s = j + 8 * (k / nx);
  by = s % ny;
  bz = s / ny;
}

// ---------------------------------------------------------------------------
// BT-layout fp16 GEMM: C = A1·B1^T (+ A2·B1^T if ASPLIT)
// A: [M,K] row-major lda, B: [N,K] row-major ldb. Tile 128x128, 4 waves.
// Twin-buffer BK=64: two 32-wide LDS buffers staged per barrier pair —
// halves barrier count, 8 GLDS in flight per drain. K must be % 64.
// EPI_SOFT: tile-local softmax epilogue, register-lean (per-row streaming).
// ---------------------------------------------------------------------------
template <bool ASPLIT, int EPI>
__global__ __launch_bounds__(256) void gemm_bt(
    const fp16_t* __restrict__ A1, const fp16_t* __restrict__ A2,
    const fp16_t* __restrict__ B1, void* __restrict__ Cv, int K, int lda,
    int ldb, long long sA, long long sB, long long sC,
    const float* __restrict__ bias, const float* __restrict__ resid,
    float* __restrict__ m_out, float* __restrict__ l_out) {
  constexpr int ALO = ASPLIT ? 128 * 32 : 0;
  __shared__ __align__(16) fp16_t As[2][128 * 32 + ALO];
  __shared__ __align__(16) fp16_t Bs[2][128 * 32];
  __shared__ float smax[(EPI == EPI_SOFT) ? 256 : 1];
  __shared__ float ssum[(EPI == EPI_SOFT) ? 256 : 1];

  const int tid  = threadIdx.x;
  const int lane = tid & 63;
  const int w    = tid >> 6;
  const int wr   = w >> 1;
  const int wc   = w & 1;

  int bx, by, bz;
  xcd_decode(bx, by, bz);
  const int N = (int)gridDim.x * 128;
  const long long tile_m = (long long)by * 128;
  const long long tile_n = (long long)bx * 128;
  const long long z = bz;
  const long long aoff = z * sA + tile_m * (long long)lda;
  const long long boff = z * sB + tile_n * (long long)ldb;

  fx4 acc[4][4];
#pragma unroll
  for (int i = 0; i < 4; i++)
#pragma unroll
    for (int j = 0; j < 4; j++) acc[i][j] = (fx4){0.f, 0.f, 0.f, 0.f};

  // staging swizzle: LDS slot m holds global chunk (m+(r>>1))&3 of row r
  const int r_l = lane >> 2;
  const int c_l = ((((lane & 3) + ((r_l >> 1) & 3)) & 3) << 3);
  const int frow = lane & 15;
  const int qoff = (((lane >> 4) - ((frow >> 1) & 3)) & 3) << 3;

  const size_t sa0 = (size_t)(w * 16 + r_l) * lda + c_l;
  const size_t sa1 = (size_t)(64 + w * 16 + r_l) * lda + c_l;
  const size_t sb0 = (size_t)(w * 16 + r_l) * ldb + c_l;
  const size_t sb1 = (size_t)(64 + w * 16 + r_l) * ldb + c_l;
  const int ld0 = (w * 16) * 32;
  const int ld1 = (64 + w * 16) * 32;

  for (int kt = 0; kt < K; kt += 64) {
    __syncthreads();
#pragma unroll
    for (int h = 0; h < 2; h++) {
      const fp16_t* gah = A1 + aoff + kt + h * 32;
      const fp16_t* gbh = B1 + boff + kt + h * 32;
      GLDS(gah + sa0, &As[h][ld0]);
      GLDS(gah + sa1, &As[h][ld1]);
      GLDS(gbh + sb0, &Bs[h][ld0]);
      GLDS(gbh + sb1, &Bs[h][ld1]);
      if (ASPLIT) {
        const fp16_t* gal = A2 + aoff + kt + h * 32;
        GLDS(gal + sa0, &As[h][ALO + ld0]);
        GLDS(gal + sa1, &As[h][ALO + ld1]);
      }
    }
    __syncthreads();

#pragma unroll
    for (int h = 0; h < 2; h++) {
      fp16x8 afh[4], bbh[4], afl[4];
#pragma unroll
      for (int mi = 0; mi < 4; mi++)
        afh[mi] = *(const fp16x8*)&As[h][(wr * 64 + mi * 16 + frow) * 32 + qoff];
#pragma unroll
      for (int ni = 0; ni < 4; ni++)
        bbh[ni] = *(const fp16x8*)&Bs[h][(wc * 64 + ni * 16 + frow) * 32 + qoff];
      if (ASPLIT) {
#pragma unroll
        for (int mi = 0; mi < 4; mi++)
          afl[mi] =
              *(const fp16x8*)&As[h][ALO + (wr * 64 + mi * 16 + frow) * 32 + qoff];
      }
#pragma unroll
      for (int mi = 0; mi < 4; mi++)
#pragma unroll
        for (int ni = 0; ni < 4; ni++) {
          fx4 a = acc[mi][ni];
          a = __builtin_amdgcn_mfma_f32_16x16x32_f16(afh[mi], bbh[ni], a, 0, 0, 0);
          if (ASPLIT)
            a = __builtin_amdgcn_mfma_f32_16x16x32_f16(afl[mi], bbh[ni], a, 0, 0, 0);
          acc[mi][ni] = a;
        }
    }
  }

  // Epilogue. C/D layout: col = lane&15, row = (lane>>4)*4 + reg  [m89/m91]
  const int er = (lane >> 4) * 4;
  const int ec = lane & 15;
  const long long crow = tile_m + wr * 64;
  const long long ccol = tile_n + wc * 64;

  if constexpr (EPI == EPI_SOFT) {
    // pass 1: mask diagonal + per-row max (streaming, no arrays)
#pragma unroll
    for (int mi = 0; mi < 4; mi++)
#pragma unroll
      for (int j = 0; j < 4; j++) {
        const long long r = crow + mi * 16 + er + j;
        float mx = -1e30f;
#pragma unroll
        for (int ni = 0; ni < 4; ni++) {
          const long long cc = ccol + ni * 16 + ec;
          float v = acc[mi][ni][j];
          if (r == cc) v = -1e30f;
          acc[mi][ni][j] = v;
          mx = fmaxf(mx, v);
        }
#pragma unroll
        for (int o = 1; o < 16; o <<= 1) mx = fmaxf(mx, __shfl_xor(mx, o, 64));
        if (ec == 0) smax[wc * 128 + wr * 64 + mi * 16 + er + j] = mx;
      }
    __syncthreads();
    // pass 2: exp + per-row sum + P' store (streaming)
#pragma unroll
    for (int mi = 0; mi < 4; mi++)
#pragma unroll
      for (int j = 0; j < 4; j++) {
        const int rid = wr * 64 + mi * 16 + er + j;
        const float m = fmaxf(smax[rid], smax[128 + rid]);
        const long long r = crow + mi * 16 + er + j;
        float s = 0.f;
#pragma unroll
        for (int ni = 0; ni < 4; ni++) {
          const float e = __expf(acc[mi][ni][j] - m);  // diag -> 0
          s += e;
          ((fp16_t*)Cv)[z * sC + r * N + (ccol + ni * 16 + ec)] = (fp16_t)e;
        }
#pragma unroll
        for (int o = 1; o < 16; o <<= 1) s += __shfl_xor(s, o, 64);
        if (ec == 0) ssum[wc * 128 + rid] = s;
      }
    __syncthreads();
    if (tid < 128) {
      const long long si = (z * 16 + bx) * 2048 + tile_m + tid;
      m_out[si] = fmaxf(smax[tid], smax[128 + tid]);
      l_out[si] = ssum[tid] + ssum[128 + tid];
    }
  } else {
#pragma unroll
    for (int mi = 0; mi < 4; mi++)
#pragma unroll
      for (int j = 0; j < 4; j++) {
        const long long r = crow + mi * 16 + er + j;
#pragma unroll
        for (int ni = 0; ni < 4; ni++) {
          const long long cc = ccol + ni * 16 + ec;
          const long long idx = z * sC + r * N + cc;
          const float v = acc[mi][ni][j];
          if (EPI == EPI_F32) {
            ((float*)Cv)[idx] = v;
          } else if (EPI == EPI_F16) {
            ((fp16_t*)Cv)[idx] = (fp16_t)v;
          } else {  // EPI_FUSE
            float u = v + bias[cc];
            u = u > 0.f ? u : 0.f;
            ((float*)Cv)[idx] = resid[r * N + cc] + u;
          }
        }
      }
  }
}

// ---------------------------------------------------------------------------
// PV GEMM: c[m,d] = sum_t scale[m, t/128] * P'[m,t] * xT[d,t]
// GLDS staging for BOTH operands (P' is row-major [2048,2048], xT [768,2048]).
// Softmax scale applied on the A-FRAGMENT after ds_read: in the MFMA A
// layout, row = wr*64+mi*16+(lane&15) is fixed per (lane,mi), and every
// 32-wide K-step lies inside one 128-col scale tile -> 4 LDS broadcasts +
// 8 packed fp16 muls per K-step. Bit-identical to staging-time scaling.
// Prologue merges per-tile stats (softmerge fused). Grid (6,16,8). K=2048.
// ---------------------------------------------------------------------------
__global__ __launch_bounds__(256) void gemm_pv(
    const fp16_t* __restrict__ P, const float* __restrict__ mstat,
    const float* __restrict__ lstat, const fp16_t* __restrict__ Bx,
    fp16_t* __restrict__ C) {
  __shared__ __align__(16) fp16_t As[2][128 * 32];
  __shared__ __align__(16) fp16_t Bs[2][128 * 32];
  __shared__ float sc[16][128];

  const int tid  = threadIdx.x;
  const int lane = tid & 63;
  const int w    = tid >> 6;
  const int wr   = w >> 1;
  const int wc   = w & 1;

  int bx, by, bz;
  xcd_decode(bx, by, bz);
  const long long tile_m = (long long)by * 128;
  const long long tile_n = (long long)bx * 128;
  const long long z = bz;

  // fused softmerge: sc[t][row] = exp(m_t - m) / l  for this block's rows
  if (tid < 128) {
    const long long base = z * 16 * 2048 + tile_m + tid;
    float mv[16];
    float m = -1e30f;
#pragma unroll
    for (int t = 0; t < 16; t++) {
      mv[t] = mstat[base + t * 2048];
      m = fmaxf(m, mv[t]);
    }
    float l = 0.f;
#pragma unroll
    for (int t = 0; t < 16; t++) l += lstat[base + t * 2048] * __expf(mv[t] - m);
    const float il = 1.0f / l;
#pragma unroll
    for (int t = 0; t < 16; t++) sc[t][tid] = __expf(mv[t] - m) * il;
  }

  fx4 acc[4][4];
#pragma unroll
  for (int i = 0; i < 4; i++)
#pragma unroll
    for (int j = 0; j < 4; j++) acc[i][j] = (fx4){0.f, 0.f, 0.f, 0.f};

  // staging swizzle (identical to gemm_bt), lda = ldb = 2048
  const int r_l = lane >> 2;
  const int c_l = ((((lane & 3) + ((r_l >> 1) & 3)) & 3) << 3);
  const int frow = lane & 15;
  const int qoff = (((lane >> 4) - ((frow >> 1) & 3)) & 3) << 3;
  const size_t s0 = (size_t)(w * 16 + r_l) * 2048 + c_l;
  const size_t s1 = (size_t)(64 + w * 16 + r_l) * 2048 + c_l;
  const int ld0 = (w * 16) * 32;
  const int ld1 = (64 + w * 16) * 32;

  const fp16_t* A = P + z * (2048LL * 2048) + tile_m * 2048;
  const fp16_t* B = Bx + z * (768LL * 2048) + tile_n * 2048;

  for (int kt = 0; kt < 2048; kt += 64) {
    __syncthreads();  // first iter: also guards sc[] writes
#pragma unroll
    for (int h = 0; h < 2; h++) {
      GLDS(A + kt + h * 32 + s0, &As[h][ld0]);
      GLDS(A + kt + h * 32 + s1, &As[h][ld1]);
      GLDS(B + kt + h * 32 + s0, &Bs[h][ld0]);
      GLDS(B + kt + h * 32 + s1, &Bs[h][ld1]);
    }
    __syncthreads();

    // per-row softmax scale for this 128-col tile (kt, kt+32 share a tile)
    fp16_t sh[4];
    {
      const int tt = kt >> 7;
#pragma unroll
      for (int mi = 0; mi < 4; mi++)
        sh[mi] = (fp16_t)sc[tt][wr * 64 + mi * 16 + frow];
    }

#pragma unroll
    for (int h = 0; h < 2; h++) {
      fp16x8 af[4], bb[4];
#pragma unroll
      for (int mi = 0; mi < 4; mi++) {
        af[mi] = *(const fp16x8*)&As[h][(wr * 64 + mi * 16 + frow) * 32 + qoff];
        af[mi] *= sh[mi];
      }
#pragma unroll
      for (int ni = 0; ni < 4; ni++)
        bb[ni] = *(const fp16x8*)&Bs[h][(wc * 64 + ni * 16 + frow) * 32 + qoff];
#pragma unroll
      for (int mi = 0; mi < 4; mi++)
#pragma unroll
        for (int ni = 0; ni < 4; ni++)
          acc[mi][ni] = __builtin_amdgcn_mfma_f32_16x16x32_f16(
              af[mi], bb[ni], acc[mi][ni], 0, 0, 0);
    }
  }

  const int er = (lane >> 4) * 4;
  const int ec = lane & 15;
  const long long crow = tile_m + wr * 64;
  const long long ccol = tile_n + wc * 64;
  fp16_t* Cz = C + z * (2048LL * 768);
#pragma unroll
  for (int mi = 0; mi < 4; mi++)
#pragma unroll
    for (int j = 0; j < 4; j++) {
      const long long rr = crow + mi * 16 + er + j;
#pragma unroll
      for (int ni = 0; ni < 4; ni++)
        Cz[rr * 768 + ccol + ni * 16 + ec] = (fp16_t)acc[mi][ni][j];
    }
}

// ---------------------------------------------------------------------------
// Fused prep: x fp32 -> xh, xl (hi/lo fp16, row-major) + xT (hi, transposed)
// ---------------------------------------------------------------------------
__global__ __launch_bounds__(256) void prep_x(
    const float* __restrict__ x, fp16_t* __restrict__ xh,
    fp16_t* __restrict__ xl, fp16_t* __restrict__ xT) {
  __shared__ fp16_t t[32][33];
  const int b = blockIdx.z;
  const int d0 = blockIdx.x * 32;
  const int s0 = blockIdx.y * 32;
  const float* ib = x + (long long)b * 2048 * 768;
  const int tx = threadIdx.x & 31;
  const int ty = threadIdx.x >> 5;
#pragma unroll
  for (int i = 0; i < 4; i++) {
    const int srow = s0 + ty + i * 8;
    const long long idx = (long long)b * 2048 * 768 + (long long)srow * 768 + d0 + tx;
    const float v = ib[(long long)srow * 768 + d0 + tx];
    const fp16_t h = (fp16_t)v;
    xh[idx] = h;
    xl[idx] = (fp16_t)(v - (float)h);
    t[ty + i * 8][tx] = h;
  }
  __syncthreads();
#pragma unroll
  for (int i = 0; i < 4; i++)
    xT[(long long)b * 768 * 2048 + (long long)(d0 + ty + i * 8) * 2048 + s0 + tx] =
        t[tx][ty + i * 8];
}

// ---------------------------------------------------------------------------
// Both weight casts in one launch: blockIdx.y selects the tensor.
// ---------------------------------------------------------------------------
__global__ __launch_bounds__(256) void cast2_f32_f16(
    const float* __restrict__ a, const float* __restrict__ b,
    fp16_t* __restrict__ oa, fp16_t* __restrict__ ob, int n4) {
  const int i = blockIdx.x * 256 + threadIdx.x;
  if (i >= n4) return;
  const float* in = blockIdx.y == 0 ? a : b;
  fp16_t* out = blockIdx.y == 0 ? oa : ob;
  const float4 v = ((const float4*)in)[i];
  ((fp16x4*)out)[i] =
      (fp16x4){(fp16_t)v.x, (fp16_t)v.y, (fp16_t)v.z, (fp16_t)v.w};
}

// ---------------------------------------------------------------------------
extern "C" void kernel_launch(void* const* d_in, const int* in_sizes, int n_in,
                              void* d_out, int out_size, void* d_ws,
                              size_t ws_size, hipStream_t stream) {
  const float* x  = (const float*)d_in[0];
  const float* W  = (const float*)d_in[1];
  const float* pw = (const float*)d_in[2];
  const float* pb = (const float*)d_in[3];

  const long long S = 2048, D = 768;
  const long long BS = 8 * S;

  // ---- workspace (~171 MB) ----
  char* p = (char*)d_ws;
  auto carve = [&](long long bytes) {
    char* q = p;
    p += (bytes + 255) & ~255LL;
    return q;
  };
  fp16_t* xh = (fp16_t*)carve(BS * D * 2);       // x hi           25.2 MB
  fp16_t* xl = (fp16_t*)carve(BS * D * 2);       // x lo (G1 only) 25.2 MB
  fp16_t* xT = (fp16_t*)carve(BS * D * 2);       // x^T (hi)       25.2 MB
  fp16_t* Wx = (fp16_t*)carve(BS * D * 2);       // Wx fp16 / c    25.2 MB
  fp16_t* Wh = (fp16_t*)carve(D * D * 2);        // W fp16          1.2 MB
  fp16_t* ph = (fp16_t*)carve(D * D * 2);        // proj_w fp16     1.2 MB
  float*  mstat = (float*)carve(BS * 16 * 4);    // per-tile max    1.0 MB
  float*  lstat = (float*)carve(BS * 16 * 4);    // per-tile sum    1.0 MB
  fp16_t* Ps = (fp16_t*)carve(8 * S * S * 2);    // P' fp16        67.1 MB
  fp16_t* cb = Wx;  // c aliases Wx: Wx fully consumed by GEMM2 before PV

  // ---- prep ----
  prep_x<<<dim3(24, 64, 8), 256, 0, stream>>>(x, xh, xl, xT);
  cast2_f32_f16<<<dim3((unsigned)(D * D / 4 / 256), 2), 256, 0, stream>>>(
      W, pw, Wh, ph, (int)(D * D / 4));

  // GEMM1 (2-term): Wx = (x_hi + x_lo) @ W^T, fp16 out
  gemm_bt<true, EPI_F16><<<dim3(6, 128, 1), 256, 0, stream>>>(
      xh, xl, Wh, Wx, 768, 768, 768, 0, 0, 0, nullptr, nullptr, nullptr,
      nullptr);

  // GEMM2 + tile-softmax: P' = exp(s - m_tile) fp16, stats m_t/l_t
  gemm_bt<false, EPI_SOFT><<<dim3(16, 16, 8), 256, 0, stream>>>(
      Wx, nullptr, xh, Ps, 768, 768, 768, S * D, S * D, S * S, nullptr,
      nullptr, mstat, lstat);

  // PV: c = (merged-scale ⊙ P') @ x  ==  A · (xT)^T, K = 2048
  gemm_pv<<<dim3(6, 16, 8), 256, 0, stream>>>(Ps, mstat, lstat, xT, cb);

  // GEMM4: out = x + relu(c @ proj_w^T + pb), fp32
  gemm_bt<false, EPI_FUSE><<<dim3(6, 128, 1), 256, 0, stream>>>(
      cb, nullptr, ph, (float*)d_out, 768, 768, 768, 0, 0, 0, pb, x, nullptr,
      nullptr);
}